// Round 5
// baseline (75.601 us; speedup 1.0000x reference)
//
#include <hip/hip_runtime.h>
#include <math.h>

#define NB 16
#define CB 256
#define MIP 8
#define EPSV 1e-5f

// K1: per (n,c) plane: row means (over w) -> xh[n][c][h], col means (over h) -> xw[n][c][w]
// All 8 float4 loads issued up-front into live registers (max MLP); all
// cross-lane reduction deferred until after the memory phase.
__global__ __launch_bounds__(256) void k_reduce(const float* __restrict__ x,
                                                const float* __restrict__ res,
                                                float* __restrict__ xh,
                                                float* __restrict__ xw) {
    int plane = blockIdx.x;                       // n*256 + c
    const float4* px4 = (const float4*)(x   + (size_t)plane * 4096);
    const float4* pr4 = (const float4*)(res + (size_t)plane * 4096);
    __shared__ float spad[256];
    int t = threadIdx.x;

    float4 a[4], b[4];
#pragma unroll
    for (int i = 0; i < 4; i++) a[i] = px4[i * 256 + t];
#pragma unroll
    for (int i = 0; i < 4; i++) b[i] = pr4[i * 256 + t];

    float csum0 = 0.f, csum1 = 0.f, csum2 = 0.f, csum3 = 0.f;
    float rsum[4];
#pragma unroll
    for (int i = 0; i < 4; i++) {
        float s0 = a[i].x + b[i].x, s1 = a[i].y + b[i].y;
        float s2 = a[i].z + b[i].z, s3 = a[i].w + b[i].w;
        csum0 += s0; csum1 += s1; csum2 += s2; csum3 += s3;
        rsum[i] = (s0 + s1) + (s2 + s3);
    }

    // rows: reduce each rsum[i] across the 16 lanes sharing row i*16+(t>>4)
#pragma unroll
    for (int i = 0; i < 4; i++) {
        float rs = rsum[i];
        rs += __shfl_xor(rs, 1);
        rs += __shfl_xor(rs, 2);
        rs += __shfl_xor(rs, 4);
        rs += __shfl_xor(rs, 8);
        rsum[i] = rs;
    }
    if ((t & 15) == 0) {
        int g = t >> 4;                           // 0..15
#pragma unroll
        for (int i = 0; i < 4; i++)
            xh[(size_t)plane * 64 + i * 16 + g] = rsum[i] * 0.015625f;
    }

    // cols: combine the 4 row-groups within each wave (lane bits 4,5), then LDS
    csum0 += __shfl_xor(csum0, 16); csum0 += __shfl_xor(csum0, 32);
    csum1 += __shfl_xor(csum1, 16); csum1 += __shfl_xor(csum1, 32);
    csum2 += __shfl_xor(csum2, 16); csum2 += __shfl_xor(csum2, 32);
    csum3 += __shfl_xor(csum3, 16); csum3 += __shfl_xor(csum3, 32);
    int wv = t >> 6;                              // wave 0..3
    int j  = t & 15;
    if ((t & 63) < 16) {
        float* d = &spad[wv * 64 + j * 4];
        d[0] = csum0; d[1] = csum1; d[2] = csum2; d[3] = csum3;
    }
    __syncthreads();
    if (t < 64)
        xw[(size_t)plane * 64 + t] =
            (spad[t] + spad[64 + t] + spad[128 + t] + spad[192 + t]) * 0.015625f;
}

// K2: per n: yl[n][m][p] = hswish(BN(W1*pool + b1)), p in [0,128)  (p<64: from xh, else xw)
__global__ __launch_bounds__(256) void k_mid_a(const float* __restrict__ xh,
                                               const float* __restrict__ xw,
                                               const float* __restrict__ w1,
                                               const float* __restrict__ b1,
                                               const float* __restrict__ gamma,
                                               const float* __restrict__ beta,
                                               const float* __restrict__ mean,
                                               const float* __restrict__ var,
                                               float* __restrict__ yl) {
    int n = blockIdx.x;
    int t = threadIdx.x;
    int p  = t & 127;
    int mg = (t >> 7) * 4;  // 0 or 4 (wave-uniform)
    const float* pool = (p < 64) ? (xh + (size_t)n * CB * 64 + p)
                                 : (xw + (size_t)n * CB * 64 + (p - 64));
    float acc[4] = {0.f, 0.f, 0.f, 0.f};
    for (int c = 0; c < CB; c++) {
        float pv = pool[(size_t)c * 64];
#pragma unroll
        for (int k = 0; k < 4; k++) acc[k] += pv * w1[(mg + k) * CB + c];
    }
#pragma unroll
    for (int k = 0; k < 4; k++) {
        int m = mg + k;
        float yv = acc[k] + b1[m];
        float inv = gamma[m] * rsqrtf(var[m] + EPSV);
        yv = (yv - mean[m]) * inv + beta[m];
        float cl = fminf(fmaxf(yv + 3.f, 0.f), 6.f);
        yl[((size_t)n * MIP + m) * 128 + p] = yv * cl * (1.f / 6.f);
    }
}

// K3: per (n,o) plane: prologue computes ah[h], aw[w] from yl/w2/w3, then
//     out = 2*wei*x + 2*res, wei = ah[h]*aw[w].  Lane-contiguous main loop.
__global__ __launch_bounds__(256) void k_apply(const float* __restrict__ x,
                                               const float* __restrict__ res,
                                               const float* __restrict__ yl,
                                               const float* __restrict__ w2,
                                               const float* __restrict__ b2,
                                               const float* __restrict__ w3,
                                               const float* __restrict__ b3,
                                               float* __restrict__ out) {
    int plane = blockIdx.x;                       // n*256 + o
    int n = plane >> 8;
    int o = plane & 255;
    const float4* px4 = (const float4*)(x   + (size_t)plane * 4096);
    const float4* pr4 = (const float4*)(res + (size_t)plane * 4096);
    float4*       po4 = (float4*)(out + (size_t)plane * 4096);
    __shared__ float sah[64], saw[64];
    int t = threadIdx.x;
    if (t < 128) {
        int hh  = t & 63;
        int off = (t < 64) ? 0 : 64;
        const float* wv = (t < 64) ? (w2 + o * MIP) : (w3 + o * MIP);
        float acc = (t < 64) ? b2[o] : b3[o];
        const float* ylp = yl + (size_t)n * MIP * 128 + off + hh;
#pragma unroll
        for (int m = 0; m < MIP; m++) acc += ylp[m * 128] * wv[m];
        float sig = 1.f / (1.f + __expf(-acc));
        if (t < 64) sah[hh] = sig; else saw[hh] = sig;
    }
    __syncthreads();
    const float4 sw4 = *(const float4*)&saw[4 * (t & 15)];
#pragma unroll
    for (int i = 0; i < 4; i++) {
        int row = i * 16 + (t >> 4);
        float ahr2 = 2.f * sah[row];
        float4 a = px4[i * 256 + t];
        float4 b = pr4[i * 256 + t];
        float4 oo;
        oo.x = a.x * (ahr2 * sw4.x) + 2.f * b.x;
        oo.y = a.y * (ahr2 * sw4.y) + 2.f * b.y;
        oo.z = a.z * (ahr2 * sw4.z) + 2.f * b.z;
        oo.w = a.w * (ahr2 * sw4.w) + 2.f * b.w;
        po4[i * 256 + t] = oo;
    }
}

extern "C" void kernel_launch(void* const* d_in, const int* in_sizes, int n_in,
                              void* d_out, int out_size, void* d_ws, size_t ws_size,
                              hipStream_t stream) {
    const float* x     = (const float*)d_in[0];
    const float* res   = (const float*)d_in[1];
    const float* w1    = (const float*)d_in[2];
    const float* b1    = (const float*)d_in[3];
    const float* gamma = (const float*)d_in[4];
    const float* beta  = (const float*)d_in[5];
    const float* mean  = (const float*)d_in[6];
    const float* var   = (const float*)d_in[7];
    const float* w2    = (const float*)d_in[8];
    const float* b2    = (const float*)d_in[9];
    const float* w3    = (const float*)d_in[10];
    const float* b3    = (const float*)d_in[11];
    float* out = (float*)d_out;

    float* ws = (float*)d_ws;
    float* xh = ws;                 // 16*256*64 = 262144 floats
    float* xw = ws + 262144;        // 262144 floats
    float* yl = ws + 524288;        // 16*8*128 = 16384 floats

    k_reduce<<<NB * CB, 256, 0, stream>>>(x, res, xh, xw);
    k_mid_a<<<NB, 256, 0, stream>>>(xh, xw, w1, b1, gamma, beta, mean, var, yl);
    k_apply<<<NB * CB, 256, 0, stream>>>(x, res, yl, w2, b2, w3, b3, out);
}